// Round 13
// baseline (501.727 us; speedup 1.0000x reference)
//
#include <hip/hip_runtime.h>

#define HID 128
#define BSHIFT 10            // 1024 dst-nodes per bucket
#define BCAP 20480           // bucket capacity (mean 16.3K, sigma ~127 -> 32 sigma)

typedef _Float16 half8 __attribute__((ext_vector_type(8)));
typedef _Float16 half4v __attribute__((ext_vector_type(4)));
typedef float f32x4 __attribute__((ext_vector_type(4)));

__device__ __forceinline__ half8 cvt8(f32x4 f0, f32x4 f1) {
  half8 h;
  h[0] = (_Float16)f0[0]; h[1] = (_Float16)f0[1];
  h[2] = (_Float16)f0[2]; h[3] = (_Float16)f0[3];
  h[4] = (_Float16)f1[0]; h[5] = (_Float16)f1[1];
  h[6] = (_Float16)f1[2]; h[7] = (_Float16)f1[3];
  return h;
}

// ---------------- graph build: two-pass binned scatter ----------------

__global__ __launch_bounds__(256) void zero_i32(int* __restrict__ p, int n) {
  int i = blockIdx.x * 256 + threadIdx.x;
  if (i < n) p[i] = 0;
}

__global__ __launch_bounds__(256) void bin_edges(const int* __restrict__ ei,
                                                 int* __restrict__ gcur,
                                                 int2* __restrict__ buf,
                                                 int E, int NB) {
  __shared__ int bcnt[128];
  __shared__ int bbase[128];
  const int tid = threadIdx.x;

  for (int chunk = blockIdx.x * 2048; chunk < E; chunk += gridDim.x * 2048) {
    if (tid < NB) bcnt[tid] = 0;
    __syncthreads();
    int s[8], d[8], slot[8], b[8];
#pragma unroll
    for (int j = 0; j < 8; ++j) {
      int e = chunk + tid + j * 256;
      if (e < E) {
        s[j] = ei[e];
        d[j] = ei[E + e];
        b[j] = d[j] >> BSHIFT;
        slot[j] = atomicAdd(&bcnt[b[j]], 1);
      } else {
        b[j] = -1;
      }
    }
    __syncthreads();
    if (tid < NB && bcnt[tid] > 0) bbase[tid] = atomicAdd(&gcur[tid], bcnt[tid]);
    __syncthreads();
#pragma unroll
    for (int j = 0; j < 8; ++j) {
      if (b[j] >= 0) {
        int pos = bbase[b[j]] + slot[j];
        if (pos < BCAP) buf[(size_t)b[j] * BCAP + pos] = make_int2(s[j], d[j]);
      }
    }
    __syncthreads();
  }
}

__global__ __launch_bounds__(256) void scatter_pad(const int2* __restrict__ buf,
                                                   const int* __restrict__ gcur,
                                                   int* __restrict__ colpad,
                                                   int* __restrict__ cnt,
                                                   float* __restrict__ dinv, int N) {
  __shared__ int lcnt[1 << BSHIFT];
  const int b = blockIdx.x;
  const int base = b << BSHIFT;
  const int tid = threadIdx.x;
  for (int i = tid; i < (1 << BSHIFT); i += 256) lcnt[i] = 0;
  __syncthreads();

  int ne = gcur[b];
  if (ne > BCAP) ne = BCAP;
  const int2* __restrict__ bb = buf + (size_t)b * BCAP;
  for (int i = tid; i < ne; i += 256) {
    int2 p = bb[i];
    int pos = atomicAdd(&lcnt[p.y - base], 1);
    if (pos < 64) colpad[(size_t)p.y * 64 + pos] = p.x;
  }
  __syncthreads();
  for (int i = tid; i < (1 << BSHIFT); i += 256) {
    int n = base + i;
    if (n < N) {
      int c = lcnt[i];
      cnt[n] = c;
      dinv[n] = rsqrtf((float)(c + 1));
    }
  }
}

// ---------------- weight convert fp32 -> f16 ----------------

__global__ __launch_bounds__(256) void cvt_w2(const float* __restrict__ a, int na,
                                              const float* __restrict__ b, int nb,
                                              _Float16* __restrict__ oa,
                                              _Float16* __restrict__ ob) {
  int i = blockIdx.x * 256 + threadIdx.x;
  if (i < na) oa[i] = (_Float16)a[i];
  else if (i < na + nb) ob[i - na] = (_Float16)b[i - na];
}

// ---------------- persistent streaming MFMA GEMM (spill-free) ----------------
// out[N][128] = A[N][K] @ W[128][K]^T.  W staged ONCE per block into LDS
// (chunk-XOR swizzle -> 2-way banks, free).  A streamed global->regs through a
// 4-slot single-ks pipeline.  PIPELINE ORDER: consume slot (MMAK) FIRST, then
// refill it for ks+4 (R12 bug: load-before-consume overwrote the live slot,
// since (ks+4)&3 == ks&3).  512 thr = 8 waves; wave = 32 rows x 128 cols.
// __launch_bounds__(512,2): allow 256 VGPRs so the ~170-reg live set does not
// spill (R11: default 128-cap -> 224MB scratch traffic, 210us).

template <int K, bool CONVA>
__global__ __launch_bounds__(512, 2) void gemm_pers(const void* __restrict__ Av,
                                                    const _Float16* __restrict__ Wh,
                                                    const float* __restrict__ bias,
                                                    const float* __restrict__ rowscale,
                                                    _Float16* __restrict__ out,
                                                    int N, int ntiles, int do_relu) {
  constexpr int KS = K / 32;                      // MFMA k-steps
  __shared__ __align__(16) char Ws[128 * K * 2];  // K=512: 128KB; K=128: 32KB

  const int tid = threadIdx.x;
  const int lane = tid & 63;
  const int wave = tid >> 6;
  const int rsel = lane & 15;  // row-within-16 / W-row selector / C col
  const int q = lane >> 4;     // k-quarter

  const float* Af = (const float*)Av;
  const _Float16* Ah = (const _Float16*)Av;

  // ---- stage W into LDS, swizzled: chunk j -> j ^ (c&7) ----
  constexpr int NCH = 128 * (K / 8);
#pragma unroll
  for (int i = 0; i < NCH / 512; ++i) {
    int ch = tid + i * 512;
    int c = ch / (K / 8);
    int j = ch % (K / 8);
    *(half8*)(Ws + (size_t)c * (K * 2) + (size_t)(j ^ (c & 7)) * 16) =
        *(const half8*)(Wh + (size_t)c * K + j * 8);
  }
  __syncthreads();

  for (int t = blockIdx.x * 8 + wave; t < ntiles; t += gridDim.x * 8) {
    const int row0 = t * 32;
    int gr0 = row0 + rsel;      if (gr0 >= N) gr0 = N - 1;
    int gr1 = row0 + 16 + rsel; if (gr1 >= N) gr1 = N - 1;
    // per-lane A base (includes q offset); per-ks byte stride: fp32=128, f16=64
    const char* a0;
    const char* a1;
    if constexpr (CONVA) {
      a0 = (const char*)(Af + (size_t)gr0 * K + q * 8);
      a1 = (const char*)(Af + (size_t)gr1 * K + q * 8);
    } else {
      a0 = (const char*)(Ah + (size_t)gr0 * K + q * 8);
      a1 = (const char*)(Ah + (size_t)gr1 * K + q * 8);
    }

    f32x4 acc[2][8];
#pragma unroll
    for (int mi = 0; mi < 2; ++mi)
#pragma unroll
      for (int ni = 0; ni < 8; ++ni) acc[mi][ni] = (f32x4){0.f, 0.f, 0.f, 0.f};

    f32x4 fb[4][2][2];  // [slot][mi][half]  (CONVA)
    half8 hb[4][2];     // [slot][mi]        (f16)

#define LOADK(SLOT, KSI)                                                     \
  do {                                                                       \
    if constexpr (CONVA) {                                                   \
      fb[SLOT][0][0] = *(const f32x4*)(a0 + (KSI) * 128);                    \
      fb[SLOT][0][1] = *(const f32x4*)(a0 + (KSI) * 128 + 16);               \
      fb[SLOT][1][0] = *(const f32x4*)(a1 + (KSI) * 128);                    \
      fb[SLOT][1][1] = *(const f32x4*)(a1 + (KSI) * 128 + 16);               \
    } else {                                                                 \
      hb[SLOT][0] = *(const half8*)(a0 + (KSI) * 64);                        \
      hb[SLOT][1] = *(const half8*)(a1 + (KSI) * 64);                        \
    }                                                                        \
  } while (0)

#define MMAK(SLOT, KSI)                                                      \
  do {                                                                       \
    half8 av0, av1;                                                          \
    if constexpr (CONVA) {                                                   \
      av0 = cvt8(fb[SLOT][0][0], fb[SLOT][0][1]);                            \
      av1 = cvt8(fb[SLOT][1][0], fb[SLOT][1][1]);                            \
    } else {                                                                 \
      av0 = hb[SLOT][0];                                                     \
      av1 = hb[SLOT][1];                                                     \
    }                                                                        \
    half8 bv[8];                                                             \
    _Pragma("unroll")                                                        \
    for (int ni = 0; ni < 8; ++ni) {                                         \
      int c = ni * 16 + rsel;                                                \
      bv[ni] = *(const half8*)(Ws + (size_t)c * (K * 2) +                    \
                               (size_t)((((KSI) * 4 + q)) ^ (c & 7)) * 16);  \
    }                                                                        \
    _Pragma("unroll")                                                        \
    for (int ni = 0; ni < 8; ++ni) {                                         \
      acc[0][ni] =                                                           \
          __builtin_amdgcn_mfma_f32_16x16x32_f16(av0, bv[ni], acc[0][ni], 0, 0, 0); \
      acc[1][ni] =                                                           \
          __builtin_amdgcn_mfma_f32_16x16x32_f16(av1, bv[ni], acc[1][ni], 0, 0, 0); \
    }                                                                        \
  } while (0)

    LOADK(0, 0);
    LOADK(1, 1);
    LOADK(2, 2);
    LOADK(3, 3);
#pragma unroll
    for (int ks = 0; ks < KS; ++ks) {
      MMAK(ks & 3, ks);                            // consume slot ks&3 (holds ks)
      if (ks + 4 < KS) LOADK((ks + 4) & 3, ks + 4);  // THEN refill it for ks+4
    }
#undef LOADK
#undef MMAK

    // epilogue: row = row0 + mi*16 + (lane>>4)*4 + j, col = ni*16 + rsel
    const int rsub = (lane >> 4) * 4;
#pragma unroll
    for (int mi = 0; mi < 2; ++mi) {
#pragma unroll
      for (int j = 0; j < 4; ++j) {
        int grow = row0 + mi * 16 + rsub + j;
        if (grow < N) {
          float rs = rowscale ? rowscale[grow] : 1.0f;
#pragma unroll
          for (int ni = 0; ni < 8; ++ni) {
            int c = ni * 16 + rsel;
            float v = acc[mi][ni][j] * rs;
            if (bias) v += bias[c];
            if (do_relu) v = fmaxf(v, 0.f);
            out[(size_t)grow * HID + c] = (_Float16)v;
          }
        }
      }
    }
  }
}

// ---------------- sparse aggregation: 4 rows per wave-instruction ----------------

__global__ __launch_bounds__(256) void agg_pad(const _Float16* __restrict__ g,
                                               const int* __restrict__ cnt,
                                               const int* __restrict__ colpad,
                                               const float* __restrict__ dinv,
                                               const float* __restrict__ bias,
                                               _Float16* __restrict__ out, int N) {
  int node = blockIdx.x * 4 + (threadIdx.x >> 6);
  if (node >= N) return;
  const int lane = threadIdx.x & 63;
  const int es = lane >> 4;   // edge slot 0..3
  const int ch = lane & 15;   // 16-byte chunk 0..15
  const int deg = cnt[node];
  const int* __restrict__ row = colpad + (size_t)node * 64;

  float acc[8] = {0.f, 0.f, 0.f, 0.f, 0.f, 0.f, 0.f, 0.f};
  int e0 = 0;
  for (; e0 + 16 <= deg; e0 += 16) {
    int i0 = row[e0 + es];
    int i1 = row[e0 + 4 + es];
    int i2 = row[e0 + 8 + es];
    int i3 = row[e0 + 12 + es];
    half8 v0 = *(const half8*)(g + (size_t)i0 * HID + ch * 8);
    half8 v1 = *(const half8*)(g + (size_t)i1 * HID + ch * 8);
    half8 v2 = *(const half8*)(g + (size_t)i2 * HID + ch * 8);
    half8 v3 = *(const half8*)(g + (size_t)i3 * HID + ch * 8);
#pragma unroll
    for (int j = 0; j < 8; ++j)
      acc[j] += ((float)v0[j] + (float)v1[j]) + ((float)v2[j] + (float)v3[j]);
  }
  for (; e0 + 4 <= deg; e0 += 4) {
    int i0 = row[e0 + es];
    half8 v0 = *(const half8*)(g + (size_t)i0 * HID + ch * 8);
#pragma unroll
    for (int j = 0; j < 8; ++j) acc[j] += (float)v0[j];
  }
  const int rem = deg - e0;   // 0..3
  float selfw = 1.0f;
  if (rem > 0) {
    int i0 = (es < rem) ? row[e0 + es] : node;  // pad slots gather the self row
    half8 v0 = *(const half8*)(g + (size_t)i0 * HID + ch * 8);
#pragma unroll
    for (int j = 0; j < 8; ++j) acc[j] += (float)v0[j];
    selfw = 1.0f - (float)(4 - rem);  // compensate the (4-rem) extra self rows
  }

#pragma unroll
  for (int j = 0; j < 8; ++j) {
    acc[j] += __shfl_xor(acc[j], 16, 64);
    acc[j] += __shfl_xor(acc[j], 32, 64);
  }

  if (lane < 16) {
    half8 sv = *(const half8*)(g + (size_t)node * HID + ch * 8);
    const float di = dinv[node];
    half8 o;
#pragma unroll
    for (int j = 0; j < 8; ++j) {
      float v = di * (acc[j] + selfw * (float)sv[j]) + bias[ch * 8 + j];
      o[j] = (_Float16)fmaxf(v, 0.f);
    }
    *(half8*)(out + (size_t)node * HID + ch * 8) = o;
  }
}

// ---------------- final GEMM (MFMA): logits[N][40] = h[N][128] @ Wl[40][128]^T + bl ----------------

__global__ __launch_bounds__(256) void gemm40_mfma(const _Float16* __restrict__ h,
                                                   const float* __restrict__ Wl,
                                                   const float* __restrict__ bl,
                                                   float* __restrict__ out, int N) {
  __shared__ __align__(16) _Float16 wlds[48][136];

  const int tid = threadIdx.x;
  const int lane = tid & 63;
  const int wave = tid >> 6;
  const int row0 = blockIdx.x * 128;

#pragma unroll
  for (int i = 0; i < 6; ++i) {
    int idx4 = tid + i * 256;
    int c = idx4 >> 5;
    int ko = (idx4 & 31) * 4;
    float4 v = make_float4(0.f, 0.f, 0.f, 0.f);
    if (c < 40) v = *(const float4*)(Wl + (size_t)c * HID + ko);
    half4v hv;
    hv[0] = (_Float16)v.x; hv[1] = (_Float16)v.y;
    hv[2] = (_Float16)v.z; hv[3] = (_Float16)v.w;
    *(half4v*)&wlds[c][ko] = hv;
  }
  __syncthreads();

  f32x4 acc[2][3] = {};
  const int arow_in = lane & 15;
  const int kq = lane >> 4;

#pragma unroll
  for (int ks = 0; ks < 4; ++ks) {
    half8 a[2], b[3];
#pragma unroll
    for (int mi = 0; mi < 2; ++mi) {
      int gr = row0 + wave * 32 + mi * 16 + arow_in;
      if (gr >= N) gr = N - 1;
      a[mi] = *(const half8*)(h + (size_t)gr * HID + ks * 32 + kq * 8);
    }
#pragma unroll
    for (int ni = 0; ni < 3; ++ni) {
      int c = ni * 16 + arow_in;
      b[ni] = *(const half8*)&wlds[c][ks * 32 + kq * 8];
    }
#pragma unroll
    for (int mi = 0; mi < 2; ++mi)
#pragma unroll
      for (int ni = 0; ni < 3; ++ni)
        acc[mi][ni] = __builtin_amdgcn_mfma_f32_16x16x32_f16(a[mi], b[ni], acc[mi][ni], 0, 0, 0);
  }

  const int rsub = (lane >> 4) * 4;
#pragma unroll
  for (int ni = 0; ni < 3; ++ni) {
    int col = ni * 16 + (lane & 15);
    if (col >= 40) continue;
    float bv = bl[col];
#pragma unroll
    for (int mi = 0; mi < 2; ++mi) {
#pragma unroll
      for (int j = 0; j < 4; ++j) {
        int gr = row0 + wave * 32 + mi * 16 + rsub + j;
        if (gr < N) out[(size_t)gr * 40 + col] = acc[mi][ni][j] + bv;
      }
    }
  }
}

// ---------------- launch ----------------

extern "C" void kernel_launch(void* const* d_in, const int* in_sizes, int n_in,
                              void* d_out, int out_size, void* d_ws, size_t ws_size,
                              hipStream_t stream) {
  const float* x = (const float*)d_in[0];
  const int* ei = (const int*)d_in[1];
  const float* W0 = (const float*)d_in[2];
  const float* b0 = (const float*)d_in[3];
  const float* Wc = (const float*)d_in[4];
  const float* bc = (const float*)d_in[5];
  const float* Wl = (const float*)d_in[6];
  const float* bl = (const float*)d_in[7];
  float* out = (float*)d_out;

  const int N = in_sizes[0] / 512;
  const int E = in_sizes[1] / 2;
  const int NB = (N + (1 << BSHIFT) - 1) >> BSHIFT;  // 98 for N=100000

  char* ws = (char*)d_ws;
  size_t off = 0;
  auto alloc = [&](size_t bytes) -> char* {
    char* p = ws + off;
    off += (bytes + 511) & ~(size_t)511;
    return p;
  };
  float* dinv = (float*)alloc((size_t)N * 4);
  int* cnt = (int*)alloc((size_t)N * 4);
  int* gcur = (int*)alloc(128 * 4);
  int* colpad = (int*)alloc((size_t)N * 64 * 4);
  int2* bbuf = (int2*)alloc((size_t)NB * BCAP * 8);
  _Float16* hA = (_Float16*)alloc((size_t)N * HID * 2);
  _Float16* hB = (_Float16*)alloc((size_t)N * HID * 2);
  _Float16* hG = (_Float16*)alloc((size_t)N * HID * 2);
  _Float16* W0h = (_Float16*)alloc((size_t)HID * 512 * 2);
  _Float16* Wch = (_Float16*)alloc((size_t)3 * HID * HID * 2);

  const int nb_g = (N + 127) / 128;
  const int ntiles = (N + 31) / 32;

  zero_i32<<<1, 256, 0, stream>>>(gcur, 128);
  bin_edges<<<512, 256, 0, stream>>>(ei, gcur, bbuf, E, NB);
  scatter_pad<<<NB, 256, 0, stream>>>(bbuf, gcur, colpad, cnt, dinv, N);

  const int nw0 = HID * 512, nwc = 3 * HID * HID;
  cvt_w2<<<(nw0 + nwc + 255) / 256, 256, 0, stream>>>(W0, nw0, Wc, nwc, W0h, Wch);

  // input layer: hA = relu(x @ W0^T + b0)   (A fp32, cvt in-flight; W in LDS)
  gemm_pers<512, true><<<256, 512, 0, stream>>>(x, W0h, b0, nullptr, hA, N, ntiles, 1);

  _Float16* bufs[2] = {hA, hB};
  int cur = 0;
  for (int l = 0; l < 3; ++l) {
    gemm_pers<128, false><<<(ntiles + 7) / 8, 512, 0, stream>>>(
        bufs[cur], Wch + (size_t)l * HID * HID, nullptr, dinv, hG, N, ntiles, 0);
    agg_pad<<<(N + 3) / 4, 256, 0, stream>>>(hG, cnt, colpad, dinv, bc + (size_t)l * HID,
                                             bufs[1 - cur], N);
    cur = 1 - cur;
  }

  gemm40_mfma<<<nb_g, 256, 0, stream>>>(bufs[cur], Wl, bl, out, N);
}

// Round 14
// 391.222 us; speedup vs baseline: 1.2825x; 1.2825x over previous
//
#include <hip/hip_runtime.h>

#define HID 128
#define BSHIFT 10            // 1024 dst-nodes per bucket
#define BCAP 20480           // bucket capacity (mean 16.3K, sigma ~127 -> 32 sigma)

typedef _Float16 half8 __attribute__((ext_vector_type(8)));
typedef _Float16 half4v __attribute__((ext_vector_type(4)));
typedef float f32x4 __attribute__((ext_vector_type(4)));

__device__ __forceinline__ half8 cvt8(f32x4 f0, f32x4 f1) {
  half8 h;
  h[0] = (_Float16)f0[0]; h[1] = (_Float16)f0[1];
  h[2] = (_Float16)f0[2]; h[3] = (_Float16)f0[3];
  h[4] = (_Float16)f1[0]; h[5] = (_Float16)f1[1];
  h[6] = (_Float16)f1[2]; h[7] = (_Float16)f1[3];
  return h;
}

// async global->LDS, 16B per lane; LDS dest = wave-uniform base + lane*16
#define GLDS16(gp, lp)                                                        \
  __builtin_amdgcn_global_load_lds(                                           \
      (const __attribute__((address_space(1))) void*)(gp),                    \
      (__attribute__((address_space(3))) void*)(lp), 16, 0, 0)

// ---------------- graph build: two-pass binned scatter ----------------

__global__ __launch_bounds__(256) void zero_i32(int* __restrict__ p, int n) {
  int i = blockIdx.x * 256 + threadIdx.x;
  if (i < n) p[i] = 0;
}

__global__ __launch_bounds__(256) void bin_edges(const int* __restrict__ ei,
                                                 int* __restrict__ gcur,
                                                 int2* __restrict__ buf,
                                                 int E, int NB) {
  __shared__ int bcnt[128];
  __shared__ int bbase[128];
  const int tid = threadIdx.x;

  for (int chunk = blockIdx.x * 2048; chunk < E; chunk += gridDim.x * 2048) {
    if (tid < NB) bcnt[tid] = 0;
    __syncthreads();
    int s[8], d[8], slot[8], b[8];
#pragma unroll
    for (int j = 0; j < 8; ++j) {
      int e = chunk + tid + j * 256;
      if (e < E) {
        s[j] = ei[e];
        d[j] = ei[E + e];
        b[j] = d[j] >> BSHIFT;
        slot[j] = atomicAdd(&bcnt[b[j]], 1);
      } else {
        b[j] = -1;
      }
    }
    __syncthreads();
    if (tid < NB && bcnt[tid] > 0) bbase[tid] = atomicAdd(&gcur[tid], bcnt[tid]);
    __syncthreads();
#pragma unroll
    for (int j = 0; j < 8; ++j) {
      if (b[j] >= 0) {
        int pos = bbase[b[j]] + slot[j];
        if (pos < BCAP) buf[(size_t)b[j] * BCAP + pos] = make_int2(s[j], d[j]);
      }
    }
    __syncthreads();
  }
}

__global__ __launch_bounds__(256) void scatter_pad(const int2* __restrict__ buf,
                                                   const int* __restrict__ gcur,
                                                   int* __restrict__ colpad,
                                                   int* __restrict__ cnt,
                                                   float* __restrict__ dinv, int N) {
  __shared__ int lcnt[1 << BSHIFT];
  const int b = blockIdx.x;
  const int base = b << BSHIFT;
  const int tid = threadIdx.x;
  for (int i = tid; i < (1 << BSHIFT); i += 256) lcnt[i] = 0;
  __syncthreads();

  int ne = gcur[b];
  if (ne > BCAP) ne = BCAP;
  const int2* __restrict__ bb = buf + (size_t)b * BCAP;
  for (int i = tid; i < ne; i += 256) {
    int2 p = bb[i];
    int pos = atomicAdd(&lcnt[p.y - base], 1);
    if (pos < 64) colpad[(size_t)p.y * 64 + pos] = p.x;
  }
  __syncthreads();
  for (int i = tid; i < (1 << BSHIFT); i += 256) {
    int n = base + i;
    if (n < N) {
      int c = lcnt[i];
      cnt[n] = c;
      dinv[n] = rsqrtf((float)(c + 1));
    }
  }
}

// ---------------- weight convert fp32 -> f16 ----------------

__global__ __launch_bounds__(256) void cvt_w2(const float* __restrict__ a, int na,
                                              const float* __restrict__ b, int nb,
                                              _Float16* __restrict__ oa,
                                              _Float16* __restrict__ ob) {
  int i = blockIdx.x * 256 + threadIdx.x;
  if (i < na) oa[i] = (_Float16)a[i];
  else if (i < na + nb) ob[i - na] = (_Float16)b[i - na];
}

// ---------------- layer-0 GEMM: hA = relu(x[N][512] @ W0h[128][512]^T + b0) ----------------
// Panel-staged: each block stages its FULL 64-row A-panel (contiguous 2KB rows,
// fp32->f16 in regs) into LDS once, then 8 x 64-k MFMA steps with B (L2-hot)
// double-buffered via global_load_lds.  512 thr = 8 waves = 4 rowgrp x 2 colhalf.

__global__ __launch_bounds__(512) void gemm512_panel(const float* __restrict__ Af,
                                                     const _Float16* __restrict__ Wh,
                                                     const float* __restrict__ b0,
                                                     _Float16* __restrict__ out, int N) {
  __shared__ __align__(16) char As[64 * 512 * 2];       // 64KB f16, chunk-XOR swizzled
  __shared__ __align__(16) char Bs[2][128 * 64 * 2];    // 2 x 16KB (64-k chunks)

  const int tid = threadIdx.x;
  const int lane = tid & 63;
  const int wave = tid >> 6;
  const int wgrp = wave & 3;        // row-group (16 rows)
  const int coff = (wave >> 2) * 64;  // col half
  const int row0 = blockIdx.x * 64;

  // ---- stage A panel: 64 rows x 512 f32, contiguous; cvt to f16 ----
#pragma unroll
  for (int p = 0; p < 8; ++p) {
    int idx = p * 512 + tid;        // float8 index, 4096 total
    int r = idx >> 6;               // 64 float8 per row
    int j = idx & 63;               // chunk within row
    int grow = row0 + r; if (grow >= N) grow = N - 1;
    const float* src = Af + (size_t)grow * 512 + j * 8;
    f32x4 f0 = *(const f32x4*)(src);
    f32x4 f1 = *(const f32x4*)(src + 4);
    *(half8*)(As + r * 1024 + ((j ^ (r & 7)) << 4)) = cvt8(f0, f1);
  }
  // ---- stage B chunk 0 (glds): 128 rows x 64 f16; 16 rows/wave, 2 instrs ----
#pragma unroll
  for (int i = 0; i < 2; ++i) {
    int r = wave * 16 + i * 8 + (lane >> 3);
    int csw = (lane & 7) ^ (r & 7);
    GLDS16(Wh + (size_t)r * 512 + csw * 8, Bs[0] + (wave * 16 + i * 8) * 128);
  }
  __syncthreads();

  f32x4 acc[4] = {};

  for (int k8 = 0; k8 < 8; ++k8) {
    if (k8 + 1 < 8) {  // prefetch next B chunk; flies through the MFMAs below
#pragma unroll
      for (int i = 0; i < 2; ++i) {
        int r = wave * 16 + i * 8 + (lane >> 3);
        int csw = (lane & 7) ^ (r & 7);
        GLDS16(Wh + (size_t)r * 512 + (k8 + 1) * 64 + csw * 8,
               Bs[(k8 + 1) & 1] + (wave * 16 + i * 8) * 128);
      }
    }
    const char* bbuf = Bs[k8 & 1];
#pragma unroll
    for (int sub = 0; sub < 2; ++sub) {
      int r = wgrp * 16 + (lane & 15);
      int ja = k8 * 8 + sub * 4 + (lane >> 4);
      half8 a = *(const half8*)(As + r * 1024 + ((ja ^ (r & 7)) << 4));
      int jb = sub * 4 + (lane >> 4);
#pragma unroll
      for (int ni = 0; ni < 4; ++ni) {
        int c = coff + ni * 16 + (lane & 15);
        half8 b = *(const half8*)(bbuf + c * 128 + ((jb ^ (c & 7)) << 4));
        acc[ni] = __builtin_amdgcn_mfma_f32_16x16x32_f16(a, b, acc[ni], 0, 0, 0);
      }
    }
    __syncthreads();  // drains B prefetch; protects buffers
  }

  // epilogue: row = row0 + wgrp*16 + (lane>>4)*4 + j, col = coff + ni*16 + (lane&15)
  const int rsub = (lane >> 4) * 4;
#pragma unroll
  for (int j = 0; j < 4; ++j) {
    int grow = row0 + wgrp * 16 + rsub + j;
    if (grow < N) {
#pragma unroll
      for (int ni = 0; ni < 4; ++ni) {
        int c = coff + ni * 16 + (lane & 15);
        float v = acc[ni][j] + b0[c];
        out[(size_t)grow * HID + c] = (_Float16)fmaxf(v, 0.f);
      }
    }
  }
}

// ---------------- mid GEMM: g = dinv * (h[N][128] @ Wc[128][128]^T) ----------------
// Whole A-panel (16KB) + whole B (32KB) staged via glds once; ONE barrier; 4 substeps.

__global__ __launch_bounds__(512) void gemm128_panel(const _Float16* __restrict__ Ah,
                                                     const _Float16* __restrict__ Wh,
                                                     const float* __restrict__ rowscale,
                                                     _Float16* __restrict__ out, int N) {
  __shared__ __align__(16) char As[64 * 128 * 2];   // 16KB
  __shared__ __align__(16) char Bs[128 * 128 * 2];  // 32KB

  const int tid = threadIdx.x;
  const int lane = tid & 63;
  const int wave = tid >> 6;
  const int wgrp = wave & 3;
  const int coff = (wave >> 2) * 64;
  const int row0 = blockIdx.x * 64;

  // A: 64 rows x 16 chunks; per wave-instr: 4 rows x 16 chunks; 2 instrs (8 rows/wave)
#pragma unroll
  for (int i = 0; i < 2; ++i) {
    int r = wave * 8 + i * 4 + (lane >> 4);
    int grow = row0 + r; if (grow >= N) grow = N - 1;
    int csw = (lane & 15) ^ (r & 7);
    GLDS16(Ah + (size_t)grow * 128 + csw * 8, As + (wave * 8 + i * 4) * 256);
  }
  // B: 128 rows x 16 chunks; 4 instrs (16 rows/wave)
#pragma unroll
  for (int i = 0; i < 4; ++i) {
    int r = wave * 16 + i * 4 + (lane >> 4);
    int csw = (lane & 15) ^ (r & 7);
    GLDS16(Wh + (size_t)r * 128 + csw * 8, Bs + (wave * 16 + i * 4) * 256);
  }
  __syncthreads();

  f32x4 acc[4] = {};
#pragma unroll
  for (int sub = 0; sub < 4; ++sub) {
    int r = wgrp * 16 + (lane & 15);
    int j = sub * 4 + (lane >> 4);
    half8 a = *(const half8*)(As + r * 256 + ((j ^ (r & 7)) << 4));
#pragma unroll
    for (int ni = 0; ni < 4; ++ni) {
      int c = coff + ni * 16 + (lane & 15);
      half8 b = *(const half8*)(Bs + c * 256 + ((j ^ (c & 7)) << 4));
      acc[ni] = __builtin_amdgcn_mfma_f32_16x16x32_f16(a, b, acc[ni], 0, 0, 0);
    }
  }

  const int rsub = (lane >> 4) * 4;
#pragma unroll
  for (int j = 0; j < 4; ++j) {
    int grow = row0 + wgrp * 16 + rsub + j;
    if (grow < N) {
      float rs = rowscale[grow];
#pragma unroll
      for (int ni = 0; ni < 4; ++ni) {
        int c = coff + ni * 16 + (lane & 15);
        out[(size_t)grow * HID + c] = (_Float16)(acc[ni][j] * rs);
      }
    }
  }
}

// ---------------- sparse aggregation: 4 rows per wave-instruction ----------------

__global__ __launch_bounds__(256) void agg_pad(const _Float16* __restrict__ g,
                                               const int* __restrict__ cnt,
                                               const int* __restrict__ colpad,
                                               const float* __restrict__ dinv,
                                               const float* __restrict__ bias,
                                               _Float16* __restrict__ out, int N) {
  int node = blockIdx.x * 4 + (threadIdx.x >> 6);
  if (node >= N) return;
  const int lane = threadIdx.x & 63;
  const int es = lane >> 4;   // edge slot 0..3
  const int ch = lane & 15;   // 16-byte chunk 0..15
  const int deg = cnt[node];
  const int* __restrict__ row = colpad + (size_t)node * 64;

  float acc[8] = {0.f, 0.f, 0.f, 0.f, 0.f, 0.f, 0.f, 0.f};
  int e0 = 0;
  for (; e0 + 16 <= deg; e0 += 16) {
    int i0 = row[e0 + es];
    int i1 = row[e0 + 4 + es];
    int i2 = row[e0 + 8 + es];
    int i3 = row[e0 + 12 + es];
    half8 v0 = *(const half8*)(g + (size_t)i0 * HID + ch * 8);
    half8 v1 = *(const half8*)(g + (size_t)i1 * HID + ch * 8);
    half8 v2 = *(const half8*)(g + (size_t)i2 * HID + ch * 8);
    half8 v3 = *(const half8*)(g + (size_t)i3 * HID + ch * 8);
#pragma unroll
    for (int j = 0; j < 8; ++j)
      acc[j] += ((float)v0[j] + (float)v1[j]) + ((float)v2[j] + (float)v3[j]);
  }
  for (; e0 + 4 <= deg; e0 += 4) {
    int i0 = row[e0 + es];
    half8 v0 = *(const half8*)(g + (size_t)i0 * HID + ch * 8);
#pragma unroll
    for (int j = 0; j < 8; ++j) acc[j] += (float)v0[j];
  }
  const int rem = deg - e0;   // 0..3
  float selfw = 1.0f;
  if (rem > 0) {
    int i0 = (es < rem) ? row[e0 + es] : node;  // pad slots gather the self row
    half8 v0 = *(const half8*)(g + (size_t)i0 * HID + ch * 8);
#pragma unroll
    for (int j = 0; j < 8; ++j) acc[j] += (float)v0[j];
    selfw = 1.0f - (float)(4 - rem);  // compensate the (4-rem) extra self rows
  }

#pragma unroll
  for (int j = 0; j < 8; ++j) {
    acc[j] += __shfl_xor(acc[j], 16, 64);
    acc[j] += __shfl_xor(acc[j], 32, 64);
  }

  if (lane < 16) {
    half8 sv = *(const half8*)(g + (size_t)node * HID + ch * 8);
    const float di = dinv[node];
    half8 o;
#pragma unroll
    for (int j = 0; j < 8; ++j) {
      float v = di * (acc[j] + selfw * (float)sv[j]) + bias[ch * 8 + j];
      o[j] = (_Float16)fmaxf(v, 0.f);
    }
    *(half8*)(out + (size_t)node * HID + ch * 8) = o;
  }
}

// ---------------- final GEMM (MFMA): logits[N][40] = h[N][128] @ Wl[40][128]^T + bl ----------------

__global__ __launch_bounds__(256) void gemm40_mfma(const _Float16* __restrict__ h,
                                                   const float* __restrict__ Wl,
                                                   const float* __restrict__ bl,
                                                   float* __restrict__ out, int N) {
  __shared__ __align__(16) _Float16 wlds[48][136];

  const int tid = threadIdx.x;
  const int lane = tid & 63;
  const int wave = tid >> 6;
  const int row0 = blockIdx.x * 128;

#pragma unroll
  for (int i = 0; i < 6; ++i) {
    int idx4 = tid + i * 256;
    int c = idx4 >> 5;
    int ko = (idx4 & 31) * 4;
    float4 v = make_float4(0.f, 0.f, 0.f, 0.f);
    if (c < 40) v = *(const float4*)(Wl + (size_t)c * HID + ko);
    half4v hv;
    hv[0] = (_Float16)v.x; hv[1] = (_Float16)v.y;
    hv[2] = (_Float16)v.z; hv[3] = (_Float16)v.w;
    *(half4v*)&wlds[c][ko] = hv;
  }
  __syncthreads();

  f32x4 acc[2][3] = {};
  const int arow_in = lane & 15;
  const int kq = lane >> 4;

#pragma unroll
  for (int ks = 0; ks < 4; ++ks) {
    half8 a[2], b[3];
#pragma unroll
    for (int mi = 0; mi < 2; ++mi) {
      int gr = row0 + wave * 32 + mi * 16 + arow_in;
      if (gr >= N) gr = N - 1;
      a[mi] = *(const half8*)(h + (size_t)gr * HID + ks * 32 + kq * 8);
    }
#pragma unroll
    for (int ni = 0; ni < 3; ++ni) {
      int c = ni * 16 + arow_in;
      b[ni] = *(const half8*)&wlds[c][ks * 32 + kq * 8];
    }
#pragma unroll
    for (int mi = 0; mi < 2; ++mi)
#pragma unroll
      for (int ni = 0; ni < 3; ++ni)
        acc[mi][ni] = __builtin_amdgcn_mfma_f32_16x16x32_f16(a[mi], b[ni], acc[mi][ni], 0, 0, 0);
  }

  const int rsub = (lane >> 4) * 4;
#pragma unroll
  for (int ni = 0; ni < 3; ++ni) {
    int col = ni * 16 + (lane & 15);
    if (col >= 40) continue;
    float bv = bl[col];
#pragma unroll
    for (int mi = 0; mi < 2; ++mi) {
#pragma unroll
      for (int j = 0; j < 4; ++j) {
        int gr = row0 + wave * 32 + mi * 16 + rsub + j;
        if (gr < N) out[(size_t)gr * 40 + col] = acc[mi][ni][j] + bv;
      }
    }
  }
}

// ---------------- launch ----------------

extern "C" void kernel_launch(void* const* d_in, const int* in_sizes, int n_in,
                              void* d_out, int out_size, void* d_ws, size_t ws_size,
                              hipStream_t stream) {
  const float* x = (const float*)d_in[0];
  const int* ei = (const int*)d_in[1];
  const float* W0 = (const float*)d_in[2];
  const float* b0 = (const float*)d_in[3];
  const float* Wc = (const float*)d_in[4];
  const float* bc = (const float*)d_in[5];
  const float* Wl = (const float*)d_in[6];
  const float* bl = (const float*)d_in[7];
  float* out = (float*)d_out;

  const int N = in_sizes[0] / 512;
  const int E = in_sizes[1] / 2;
  const int NB = (N + (1 << BSHIFT) - 1) >> BSHIFT;  // 98 for N=100000

  char* ws = (char*)d_ws;
  size_t off = 0;
  auto alloc = [&](size_t bytes) -> char* {
    char* p = ws + off;
    off += (bytes + 511) & ~(size_t)511;
    return p;
  };
  float* dinv = (float*)alloc((size_t)N * 4);
  int* cnt = (int*)alloc((size_t)N * 4);
  int* gcur = (int*)alloc(128 * 4);
  int* colpad = (int*)alloc((size_t)N * 64 * 4);
  int2* bbuf = (int2*)alloc((size_t)NB * BCAP * 8);
  _Float16* hA = (_Float16*)alloc((size_t)N * HID * 2);
  _Float16* hB = (_Float16*)alloc((size_t)N * HID * 2);
  _Float16* hG = (_Float16*)alloc((size_t)N * HID * 2);
  _Float16* W0h = (_Float16*)alloc((size_t)HID * 512 * 2);
  _Float16* Wch = (_Float16*)alloc((size_t)3 * HID * HID * 2);

  const int nb_g = (N + 127) / 128;
  const int nb64 = (N + 63) / 64;

  zero_i32<<<1, 256, 0, stream>>>(gcur, 128);
  bin_edges<<<512, 256, 0, stream>>>(ei, gcur, bbuf, E, NB);
  scatter_pad<<<NB, 256, 0, stream>>>(bbuf, gcur, colpad, cnt, dinv, N);

  const int nw0 = HID * 512, nwc = 3 * HID * HID;
  cvt_w2<<<(nw0 + nwc + 255) / 256, 256, 0, stream>>>(W0, nw0, Wc, nwc, W0h, Wch);

  // input layer: hA = relu(x @ W0^T + b0)
  gemm512_panel<<<nb64, 512, 0, stream>>>(x, W0h, b0, hA, N);

  _Float16* bufs[2] = {hA, hB};
  int cur = 0;
  for (int l = 0; l < 3; ++l) {
    gemm128_panel<<<nb64, 512, 0, stream>>>(bufs[cur], Wch + (size_t)l * HID * HID,
                                            dinv, hG, N);
    agg_pad<<<(N + 3) / 4, 256, 0, stream>>>(hG, cnt, colpad, dinv, bc + (size_t)l * HID,
                                             bufs[1 - cur], N);
    cur = 1 - cur;
  }

  gemm40_mfma<<<nb_g, 256, 0, stream>>>(bufs[cur], Wl, bl, out, N);
}